// Round 5
// baseline (30307.977 us; speedup 1.0000x reference)
//
#include <hip/hip_runtime.h>
#include <math.h>

#define BATCH 128
#define TSTEPS 1024
#define INSZ 256
#define HSZ 256
#define MEMN 128

#define NWG_A 128
#define NWG_B 64
#define NWG_C 32
#define NWG 224
#define NTHR 256

#define GATE_C 0.40131233988754794f
#define OMG_C  (1.0f - GATE_C)
#define GAMMA_C 0.3f

// ---- per-step state, unique slot per t (write-through produced, cached-read consumed) ----
__device__ float g_hT[(size_t)TSTEPS * HSZ * BATCH];   // hT(t)[j][b]  (for C)
__device__ float g_hB[(size_t)TSTEPS * BATCH * HSZ];   // h(t)[b][j]   (for A staging, B)
__device__ float g_M [(size_t)TSTEPS * MEMN * HSZ];    // M(t)[m][j], slots 1..1023
__device__ float g_Mn[(size_t)TSTEPS * MEMN];          // Mn(t)[m],  slots 1..1023
__device__ float g_ww[(size_t)TSTEPS * BATCH * MEMN];  // ww(t)[b][m], slots 1..1023
// ---- per-WG completion flags: NO RMWs anywhere (plain bypass stores + scans) ----
__device__ int g_fA[TSTEPS * NWG_A];
__device__ int g_fB[TSTEPS * NWG_B];
__device__ int g_fC[TSTEPS * NWG_C];

__global__ void reset_ctrl_kernel() {
    const int gt = blockIdx.x * 256 + threadIdx.x, gn = gridDim.x * 256;
    for (int i = gt; i < TSTEPS * NWG_A; i += gn)
        __hip_atomic_store(&g_fA[i], 0, __ATOMIC_RELAXED, __HIP_MEMORY_SCOPE_AGENT);
    for (int i = gt; i < TSTEPS * NWG_B; i += gn)
        __hip_atomic_store(&g_fB[i], 0, __ATOMIC_RELAXED, __HIP_MEMORY_SCOPE_AGENT);
    for (int i = gt; i < TSTEPS * NWG_C; i += gn)
        __hip_atomic_store(&g_fC[i], 0, __ATOMIC_RELAXED, __HIP_MEMORY_SCOPE_AGENT);
}

__device__ __forceinline__ float sigf(float x) { return 1.0f / (1.0f + expf(-x)); }

__device__ __forceinline__ void st_wt(float* p, float v) {
    __hip_atomic_store(p, v, __ATOMIC_RELAXED, __HIP_MEMORY_SCOPE_AGENT);
}
__device__ __forceinline__ void st_wt2(float* p, float lo, float hi) {
    unsigned long long pk = (unsigned long long)__float_as_uint(lo) |
                            ((unsigned long long)__float_as_uint(hi) << 32);
    __hip_atomic_store((unsigned long long*)p, pk, __ATOMIC_RELAXED, __HIP_MEMORY_SCOPE_AGENT);
}
__device__ __forceinline__ void st_flag(int* p, int v) {
    __hip_atomic_store(p, v, __ATOMIC_RELAXED, __HIP_MEMORY_SCOPE_AGENT);
}
__device__ __forceinline__ void wait_vm0() { asm volatile("s_waitcnt vmcnt(0)" ::: "memory"); }

// wave-cooperative flag scan: each lane checks n/64 slots
__device__ __forceinline__ void wait_flags(int* f, int n, int want, int lane) {
    int it = 0;
    for (;;) {
        bool ok = true;
        for (int i = lane; i < n; i += 64)
            ok &= (__hip_atomic_load(&f[i], __ATOMIC_RELAXED, __HIP_MEMORY_SCOPE_AGENT) == want);
        if (__all(ok)) break;
        __builtin_amdgcn_s_sleep(1);
        if (++it > (1 << 22)) break;  // hang valve
    }
}

__global__ void __launch_bounds__(NTHR, 1)
mann_persist(const float* __restrict__ X, const float* __restrict__ Wih,
             const float* __restrict__ Whh, const float* __restrict__ bih,
             const float* __restrict__ bhh, float* __restrict__ out) {
    __shared__ float4 s_xt[2][4096];   // A: xh k-tiles [128 b][32 f4] XOR-swizzled (2x64 KB); B/C alias
    __shared__ float4 s_w[1024];       // A: resident weights [8 rows][128 f4] (16 KB)
    __shared__ float s_tr[256];        // A: h transpose staging
    __shared__ float s_red8[8];
    __shared__ unsigned long long s_redu8[8];

    const int w = blockIdx.x, tid = threadIdx.x;
    const int lane = tid & 63, wv = tid >> 6;
    float* s_aux = (float*)s_xt;       // B/C small carve

    // ---- reductions ----
    auto red256sum = [&](float v) -> float {
#pragma unroll
        for (int o = 32; o; o >>= 1) v += __shfl_xor(v, o, 64);
        if (lane == 0) s_red8[wv] = v;
        __syncthreads();
        float r = (s_red8[0] + s_red8[1]) + (s_red8[2] + s_red8[3]);
        __syncthreads();
        return r;
    };
    auto grpsum = [&](float v) -> float {
#pragma unroll
        for (int o = 32; o; o >>= 1) v += __shfl_xor(v, o, 64);
        if (lane == 0) s_red8[wv] = v;
        __syncthreads();
        float r = s_red8[(tid >> 7) * 2] + s_red8[(tid >> 7) * 2 + 1];
        __syncthreads();
        return r;
    };
    auto grpmax = [&](float v) -> float {
#pragma unroll
        for (int o = 32; o; o >>= 1) v = fmaxf(v, __shfl_xor(v, o, 64));
        if (lane == 0) s_red8[wv] = v;
        __syncthreads();
        float r = fmaxf(s_red8[(tid >> 7) * 2], s_red8[(tid >> 7) * 2 + 1]);
        __syncthreads();
        return r;
    };
    auto grpminu = [&](unsigned long long v) -> unsigned long long {
#pragma unroll
        for (int o = 32; o; o >>= 1) {
            unsigned long long o2 = __shfl_xor(v, o, 64);
            v = (o2 < v) ? o2 : v;
        }
        if (lane == 0) s_redu8[wv] = v;
        __syncthreads();
        unsigned long long a = s_redu8[(tid >> 7) * 2], b2 = s_redu8[(tid >> 7) * 2 + 1];
        unsigned long long r = (a < b2) ? a : b2;
        __syncthreads();
        return r;
    };

    if (w < NWG_A) {
        // ================= phase A: LSTM cell, weights LDS-resident =================
        const int j2 = wv >> 1, bh = wv & 1;
        const int bA = bh * 64 + lane;       // this thread's batch
        const int jA = 2 * w + j2;           // this thread's j
        float biasA[4];
#pragma unroll
        for (int g = 0; g < 4; ++g) biasA[g] = bih[g * HSZ + jA] + bhh[g * HSZ + jA];

        // resident weights: 8 rows (4 gates x 2 j), 512 k each = 16 KB
#pragma unroll
        for (int rep = 0; rep < 4; ++rep) {
            const int id = rep * 256 + tid;
            const int r = id >> 7, c = id & 127;
            const int grow = (r >> 1) * HSZ + 2 * w + (r & 1);
            float4 v;
            if (c < 64) v = ((const float4*)(Wih + (size_t)grow * INSZ))[c];
            else        v = ((const float4*)(Whh + (size_t)grow * HSZ))[c - 64];
            s_w[r * 128 + c] = v;
        }

        auto stageX = [&](int t, int kt, float4* buf) {
#pragma unroll
            for (int rep = 0; rep < 16; ++rep) {
                const int id = rep * 256 + tid;
                const int b = id >> 5, c = id & 31;
                buf[b * 32 + (c ^ (b & 7))] =
                    *(const float4*)(X + ((size_t)b * TSTEPS + t) * INSZ + kt * 128 + c * 4);
            }
        };
        auto loadH = [&](int tprev, int jt, float4 (&hvr)[16]) {
#pragma unroll
            for (int rep = 0; rep < 16; ++rep) {
                const int id = rep * 256 + tid;
                const int b = id >> 5, c = id & 31;
                hvr[rep] = *(const float4*)(g_hB + ((size_t)tprev * BATCH + b) * HSZ + jt * 128 + c * 4);
            }
        };
        auto writeTile = [&](float4 (&hvr)[16], float4* buf) {
#pragma unroll
            for (int rep = 0; rep < 16; ++rep) {
                const int id = rep * 256 + tid;
                const int b = id >> 5, c = id & 31;
                buf[b * 32 + (c ^ (b & 7))] = hvr[rep];
            }
        };
        auto computeTile = [&](const float4* buf, int T, float (&zacc)[4]) {
#pragma unroll 8
            for (int c = 0; c < 32; ++c) {
                const float4 xv = buf[bA * 32 + (c ^ (bA & 7))];
#pragma unroll
                for (int g = 0; g < 4; ++g) {
                    const float4 wv4 = s_w[(g * 2 + j2) * 128 + T * 32 + c];  // wave-uniform
                    zacc[g] += wv4.x * xv.x + wv4.y * xv.y + wv4.z * xv.z + wv4.w * xv.w;
                }
            }
        };

        stageX(0, 0, s_xt[0]);
        stageX(0, 1, s_xt[1]);
        __syncthreads();
        float creg = 0.f;

        for (int t = 0; t < TSTEPS; ++t) {
            if (t > 0) {
                if (wv == 0) wait_flags(g_fA + (size_t)(t - 1) * NWG_A, NWG_A, t, lane);
                __syncthreads();
                asm volatile("" ::: "memory");
            }
            float zacc[4] = {0.f, 0.f, 0.f, 0.f};
            float4 hvr[16];
            if (t > 0) loadH(t - 1, 0, hvr);       // issue h-tile0 (hides under x0 compute)
            else { const float4 z4 = make_float4(0.f,0.f,0.f,0.f);
#pragma unroll
                   for (int r = 0; r < 16; ++r) hvr[r] = z4; }
            computeTile(s_xt[0], 0, zacc);          // x k 0..127
            __syncthreads();
            writeTile(hvr, s_xt[0]);                // h j 0..127 -> buf0
            if (t > 0) loadH(t - 1, 1, hvr);
            computeTile(s_xt[1], 1, zacc);          // x k 128..255
            __syncthreads();
            writeTile(hvr, s_xt[1]);                // h j 128..255 -> buf1
            computeTile(s_xt[0], 2, zacc);          // h j 0..127
            __syncthreads();
            computeTile(s_xt[1], 3, zacc);          // h j 128..255
            // ---- activations, fully in-thread ----
            float z[4];
#pragma unroll
            for (int g = 0; g < 4; ++g) z[g] = zacc[g] + biasA[g];
            const float cn = sigf(z[1]) * creg + sigf(z[0]) * tanhf(z[2]);
            const float hn = sigf(z[3]) * tanhf(cn);
            creg = cn;
            st_wt(&g_hT[((size_t)t * HSZ + jA) * BATCH + bA], hn);
            s_tr[j2 * 128 + bA] = hn;
            __syncthreads();
            if (tid < 128)
                st_wt2(&g_hB[((size_t)t * BATCH + tid) * HSZ + 2 * w], s_tr[tid], s_tr[128 + tid]);
            wait_vm0();
            __syncthreads();
            if (tid == 0) st_flag(&g_fA[(size_t)t * NWG_A + w], t + 1);
            if (t + 1 < TSTEPS) {
                stageX(t + 1, 0, s_xt[0]);
                stageX(t + 1, 1, s_xt[1]);
            }
        }
    } else if (w < NWG_A + NWG_B) {
        // ================= phase B: read head + output + w_u/w_w =================
        const int bwg = w - NWG_A;
        const int grp = tid >> 7, lm = tid & 127;
        const int bB = bwg * 2 + grp;
        float* s_h2 = s_aux;          // [2][256]
        float* s_wr2 = s_aux + 512;   // [2][128]
        float wwreg = (lm == 0) ? OMG_C : 0.f;
        float wureg = 0.f;

        for (int t = 0; t < TSTEPS; ++t) {
            if (wv == 0) wait_flags(g_fA + (size_t)t * NWG_A, NWG_A, t + 1, lane);
            else if (wv == 1 && t > 0) wait_flags(g_fC + (size_t)(t - 1) * NWG_C, NWG_C, t, lane);
            __syncthreads();
            asm volatile("" ::: "memory");
            s_h2[grp * 256 + lm] = g_hB[((size_t)t * BATCH + bB) * HSZ + lm];
            s_h2[grp * 256 + 128 + lm] = g_hB[((size_t)t * BATCH + bB) * HSZ + 128 + lm];
            __syncthreads();
            const float hv0 = s_h2[grp * 256 + lm], hv1 = s_h2[grp * 256 + lm + 128];
            const float hnorm = sqrtf(grpsum(hv0 * hv0 + hv1 * hv1));
            float sc = 0.f;
            if (t > 0) {
                const float4* mrow = (const float4*)&g_M[((size_t)t * MEMN + lm) * HSZ];
                const float4* h4 = (const float4*)&s_h2[grp * 256];
                float a = 0.f;
#pragma unroll 8
                for (int c = 0; c < 64; ++c) {
                    const float4 m4 = mrow[c], x4 = h4[c];
                    a += m4.x * x4.x + m4.y * x4.y + m4.z * x4.z + m4.w * x4.w;
                }
                const float mn = g_Mn[(size_t)t * MEMN + lm];
                sc = a / (hnorm * mn + 1e-8f);
            }
            const float mx = grpmax(sc);
            const float ev = expf(sc - mx);
            const float es = grpsum(ev);
            const float wr = ev / es;
            s_wr2[grp * 128 + lm] = wr;
            __syncthreads();
            float rd0 = 0.f, rd1 = 0.f;
            if (t > 0) {
#pragma unroll 8
                for (int m = 0; m < 128; ++m) {
                    const float mv = g_M[((size_t)t * MEMN + m) * HSZ + tid];
                    rd0 += s_wr2[m] * mv;
                    rd1 += s_wr2[128 + m] * mv;
                }
            }
            const int b0 = bwg * 2, b1 = b0 + 1;
            float* o0 = out + ((size_t)b0 * TSTEPS + t) * 512;
            float* o1 = out + ((size_t)b1 * TSTEPS + t) * 512;
            o0[tid] = s_h2[tid];
            o1[tid] = s_h2[256 + tid];
            o0[256 + tid] = rd0;
            o1[256 + tid] = rd1;
            // w_u(t+1) = l2norm(gamma*w_u + w_r + w_w(t)); w_w(t+1) from argmin
            const float un = GAMMA_C * wureg + wr + wwreg;
            const float un2 = grpsum(un * un);
            const float us = 1.0f / fmaxf(sqrtf(un2), 1e-12f);
            const float wun = un * us;
            wureg = wun;
            unsigned long long key =
                (((unsigned long long)__float_as_uint(wun)) << 32) | (unsigned)lm;
            const unsigned long long mk = grpminu(key);
            const int amin = (int)(mk & 0xffffffffu);
            const float wwn = GATE_C * wr + ((lm == amin) ? OMG_C : 0.f);
            wwreg = wwn;
            if (t + 1 < TSTEPS)
                st_wt(&g_ww[((size_t)(t + 1) * BATCH + bB) * MEMN + lm], wwn);
            wait_vm0();
            __syncthreads();
            if (tid == 0) st_flag(&g_fB[(size_t)t * NWG_B + bwg], t + 1);
        }
    } else {
        // ================= phase C: M(t+1) = l2norm(M(t) + ww(t)^T h(t)) =================
        const int cwg = w - NWG_A - NWG_B;
        const int m0 = cwg * 4;
        float* s_wwc = s_aux;  // [4][128]
        float mreg[4] = {0.f, 0.f, 0.f, 0.f};  // own M rows stay in registers

        for (int t = 0; t < TSTEPS - 1; ++t) {
            if (wv == 0) wait_flags(g_fA + (size_t)t * NWG_A, NWG_A, t + 1, lane);
            else if (wv == 1 && t > 0) wait_flags(g_fB + (size_t)(t - 1) * NWG_B, NWG_B, t, lane);
            __syncthreads();
            asm volatile("" ::: "memory");
#pragma unroll
            for (int e = tid; e < 512; e += 256) {
                const int mi = e & 3, b = e >> 2;
                float v;
                if (t > 0) v = g_ww[((size_t)t * BATCH + b) * MEMN + m0 + mi];
                else v = (m0 + mi == 0) ? OMG_C : 0.f;
                s_wwc[mi * 128 + b] = v;
            }
            __syncthreads();
            float macc[4];
#pragma unroll
            for (int mi = 0; mi < 4; ++mi) macc[mi] = mreg[mi];
            const float4* ht4 = (const float4*)&g_hT[((size_t)t * HSZ + tid) * BATCH];
#pragma unroll 4
            for (int b4 = 0; b4 < 32; ++b4) {
                const float4 hv4 = ht4[b4];
#pragma unroll
                for (int mi = 0; mi < 4; ++mi) {
                    const float* wc = &s_wwc[mi * 128 + b4 * 4];
                    macc[mi] += wc[0] * hv4.x + wc[1] * hv4.y + wc[2] * hv4.z + wc[3] * hv4.w;
                }
            }
#pragma unroll
            for (int mi = 0; mi < 4; ++mi) {
                const float nrm = sqrtf(red256sum(macc[mi] * macc[mi]));
                const float scale = 1.0f / fmaxf(nrm, 1e-12f);
                const float vo = macc[mi] * scale;
                mreg[mi] = vo;
                st_wt(&g_M[((size_t)(t + 1) * MEMN + m0 + mi) * HSZ + tid], vo);
                if (tid == 0) st_wt(&g_Mn[(size_t)(t + 1) * MEMN + m0 + mi], nrm * scale);
            }
            wait_vm0();
            __syncthreads();
            if (tid == 0) st_flag(&g_fC[(size_t)t * NWG_C + cwg], t + 1);
        }
    }
}

extern "C" void kernel_launch(void* const* d_in, const int* in_sizes, int n_in,
                              void* d_out, int out_size, void* d_ws, size_t ws_size,
                              hipStream_t stream) {
    const float* X   = (const float*)d_in[0];
    const float* Wih = (const float*)d_in[1];
    const float* Whh = (const float*)d_in[2];
    const float* bih = (const float*)d_in[3];
    const float* bhh = (const float*)d_in[4];
    float* out = (float*)d_out;
    (void)in_sizes; (void)n_in; (void)out_size; (void)d_ws; (void)ws_size;

    hipLaunchKernelGGL(reset_ctrl_kernel, dim3(224), dim3(256), 0, stream);
    hipLaunchKernelGGL(mann_persist, dim3(NWG), dim3(NTHR), 0, stream,
                       X, Wih, Whh, bih, bhh, out);
}

// Round 6
// 24681.888 us; speedup vs baseline: 1.2279x; 1.2279x over previous
//
#include <hip/hip_runtime.h>
#include <math.h>

#define BATCH 128
#define TSTEPS 1024
#define INSZ 256
#define HSZ 256
#define MEMN 128

#define NWG_A 128
#define NWG_B 64
#define NWG_C 32
#define NWG 224
#define NTHR 256

#define GATE_C 0.40131233988754794f
#define OMG_C  (1.0f - GATE_C)
#define GAMMA_C 0.3f

// ---- per-step state, unique slot per t (write-through produced, cached-read consumed) ----
__device__ float g_hT[(size_t)TSTEPS * HSZ * BATCH];   // hT(t)[j][b]
__device__ float g_M [(size_t)TSTEPS * MEMN * HSZ];    // M(t)[m][j], slots 1..1023
__device__ float g_Mn[(size_t)TSTEPS * MEMN];          // Mn(t)[m],  slots 1..1023
__device__ float g_ww[(size_t)TSTEPS * BATCH * MEMN];  // ww(t)[b][m], slots 1..1023
__device__ float g_c[BATCH * HSZ];                     // private per A-thread (cached)
// ---- per-WG completion flags: NO RMWs anywhere (plain bypass stores + scans) ----
__device__ int g_fA[TSTEPS * NWG_A];
__device__ int g_fB[TSTEPS * NWG_B];
__device__ int g_fC[TSTEPS * NWG_C];

__global__ void reset_ctrl_kernel() {
    const int gt = blockIdx.x * 256 + threadIdx.x, gn = gridDim.x * 256;
    for (int i = gt; i < TSTEPS * NWG_A; i += gn)
        __hip_atomic_store(&g_fA[i], 0, __ATOMIC_RELAXED, __HIP_MEMORY_SCOPE_AGENT);
    for (int i = gt; i < TSTEPS * NWG_B; i += gn)
        __hip_atomic_store(&g_fB[i], 0, __ATOMIC_RELAXED, __HIP_MEMORY_SCOPE_AGENT);
    for (int i = gt; i < TSTEPS * NWG_C; i += gn)
        __hip_atomic_store(&g_fC[i], 0, __ATOMIC_RELAXED, __HIP_MEMORY_SCOPE_AGENT);
}

__device__ __forceinline__ float sigf(float x) { return 1.0f / (1.0f + expf(-x)); }

__device__ __forceinline__ void st_wt(float* p, float v) {
    __hip_atomic_store(p, v, __ATOMIC_RELAXED, __HIP_MEMORY_SCOPE_AGENT);
}
__device__ __forceinline__ void st_flag(int* p, int v) {
    __hip_atomic_store(p, v, __ATOMIC_RELAXED, __HIP_MEMORY_SCOPE_AGENT);
}
__device__ __forceinline__ void wait_vm0() { asm volatile("s_waitcnt vmcnt(0)" ::: "memory"); }

// wave-cooperative flag scan: each lane checks n/64 slots
__device__ __forceinline__ void wait_flags(int* f, int n, int want, int lane) {
    int it = 0;
    for (;;) {
        bool ok = true;
        for (int i = lane; i < n; i += 64)
            ok &= (__hip_atomic_load(&f[i], __ATOMIC_RELAXED, __HIP_MEMORY_SCOPE_AGENT) == want);
        if (__all(ok)) break;
        __builtin_amdgcn_s_sleep(1);
        if (++it > (1 << 22)) break;  // hang valve
    }
}

__global__ void __launch_bounds__(NTHR, 1)
mann_persist(const float* __restrict__ X, const float* __restrict__ Wih,
             const float* __restrict__ Whh, const float* __restrict__ bih,
             const float* __restrict__ bhh, float* __restrict__ out) {
    __shared__ float4 s_x4[64 * 128];   // A: xh tiles (128 KB); B aliases as s_M
    __shared__ float s_aux[4096];       // A: partials; B/C carve
    __shared__ float s_red8[8];
    __shared__ float s_red16[16];
    __shared__ unsigned long long s_redu8[8];

    const int w = blockIdx.x, tid = threadIdx.x;
    const int lane = tid & 63, wv = tid >> 6;

    // ---- reductions ----
    auto grpsum = [&](float v) -> float {
#pragma unroll
        for (int o = 32; o; o >>= 1) v += __shfl_xor(v, o, 64);
        if (lane == 0) s_red8[wv] = v;
        __syncthreads();
        float r = s_red8[(tid >> 7) * 2] + s_red8[(tid >> 7) * 2 + 1];
        __syncthreads();
        return r;
    };
    auto grpmax = [&](float v) -> float {
#pragma unroll
        for (int o = 32; o; o >>= 1) v = fmaxf(v, __shfl_xor(v, o, 64));
        if (lane == 0) s_red8[wv] = v;
        __syncthreads();
        float r = fmaxf(s_red8[(tid >> 7) * 2], s_red8[(tid >> 7) * 2 + 1]);
        __syncthreads();
        return r;
    };
    auto grpminu = [&](unsigned long long v) -> unsigned long long {
#pragma unroll
        for (int o = 32; o; o >>= 1) {
            unsigned long long o2 = __shfl_xor(v, o, 64);
            v = (o2 < v) ? o2 : v;
        }
        if (lane == 0) s_redu8[wv] = v;
        __syncthreads();
        unsigned long long a = s_redu8[(tid >> 7) * 2], b2 = s_redu8[(tid >> 7) * 2 + 1];
        unsigned long long r = (a < b2) ? a : b2;
        __syncthreads();
        return r;
    };
    // batched 4-value block-sum: same order as R4's red256sum per component
    auto red256sum4 = [&](float v0, float v1, float v2, float v3, float (&r)[4]) {
#pragma unroll
        for (int o = 32; o; o >>= 1) {
            v0 += __shfl_xor(v0, o, 64);
            v1 += __shfl_xor(v1, o, 64);
            v2 += __shfl_xor(v2, o, 64);
            v3 += __shfl_xor(v3, o, 64);
        }
        if (lane == 0) {
            s_red16[wv * 4 + 0] = v0; s_red16[wv * 4 + 1] = v1;
            s_red16[wv * 4 + 2] = v2; s_red16[wv * 4 + 3] = v3;
        }
        __syncthreads();
#pragma unroll
        for (int k = 0; k < 4; ++k)
            r[k] = (s_red16[0 * 4 + k] + s_red16[1 * 4 + k]) +
                   (s_red16[2 * 4 + k] + s_red16[3 * 4 + k]);
        __syncthreads();
    };

    if (w < NWG_A) {
        // ================= phase A: LSTM cell (identical to R4) =================
        const int bb = w >> 6, jb = w & 63;
        const int bglob = bb * 64 + lane;
        float biasA[4];
#pragma unroll
        for (int g = 0; g < 4; ++g) {
            const int row = g * HSZ + jb * 4 + wv;
            biasA[g] = bih[row] + bhh[row];
        }

        auto stageX = [&](int t) {
            const int kq = tid & 63, bofs = tid >> 6;
#pragma unroll 4
            for (int rep = 0; rep < 16; ++rep) {
                const int b = rep * 4 + bofs;
                const float4 v = *(const float4*)(X + ((size_t)(bb * 64 + b) * TSTEPS + t) * INSZ + kq * 4);
                s_x4[b * 128 + (kq ^ (b & 7))] = v;
            }
        };
        auto computeRegion = [&](float (&acc)[16], const float* __restrict__ Wb, const int kofs) {
            const int kbase = kofs + wv * 64;
#pragma unroll 4
            for (int k4 = 0; k4 < 16; ++k4) {
                const int kg = kbase + k4 * 4;
                const float4 xv = s_x4[lane * 128 + ((kg >> 2) ^ (lane & 7))];
                const int kl = kg - kofs;
#pragma unroll
                for (int rr = 0; rr < 16; ++rr) {
                    const int grow = (rr >> 2) * HSZ + jb * 4 + (rr & 3);
                    const float4 wv4 = *(const float4*)(Wb + (size_t)grow * 256 + kl);
                    acc[rr] += wv4.x * xv.x + wv4.y * xv.y + wv4.z * xv.z + wv4.w * xv.w;
                }
            }
        };

        stageX(0);
        __syncthreads();

        for (int t = 0; t < TSTEPS; ++t) {
            float acc[16];
#pragma unroll
            for (int i = 0; i < 16; ++i) acc[i] = 0.f;
            float4 hv[16];
            if (t > 0) {
                if (wv == 0) wait_flags(g_fA + (size_t)(t - 1) * NWG_A, NWG_A, t, lane);
                __syncthreads();
                asm volatile("" ::: "memory");
#pragma unroll
                for (int rep = 0; rep < 16; ++rep) {
                    const int j0 = (wv * 16 + rep) * 4;
                    const size_t base = ((size_t)(t - 1) * HSZ + j0) * BATCH + bglob;
                    float4 v;
                    v.x = g_hT[base];
                    v.y = g_hT[base + BATCH];
                    v.z = g_hT[base + 2 * BATCH];
                    v.w = g_hT[base + 3 * BATCH];
                    hv[rep] = v;
                }
            }
            computeRegion(acc, Wih, 0);
            if (t > 0) {
#pragma unroll
                for (int rep = 0; rep < 16; ++rep)
                    s_x4[lane * 128 + ((64 + wv * 16 + rep) ^ (lane & 7))] = hv[rep];
            } else {
                const float4 z4 = make_float4(0.f, 0.f, 0.f, 0.f);
#pragma unroll
                for (int rep = 0; rep < 16; ++rep)
                    s_x4[lane * 128 + ((64 + wv * 16 + rep) ^ (lane & 7))] = z4;
            }
            __syncthreads();
            computeRegion(acc, Whh, 256);
#pragma unroll
            for (int rr = 0; rr < 16; ++rr) s_aux[(wv * 16 + rr) * 64 + lane] = acc[rr];
            __syncthreads();
            float z[4];
#pragma unroll
            for (int g = 0; g < 4; ++g) {
                const int rr = g * 4 + wv;
                z[g] = ((s_aux[rr * 64 + lane] + s_aux[(16 + rr) * 64 + lane]) +
                        (s_aux[(32 + rr) * 64 + lane] + s_aux[(48 + rr) * 64 + lane])) + biasA[g];
            }
            const int jglob = jb * 4 + wv;
            const int cidx = bglob * HSZ + jglob;
            const float cold = (t == 0) ? 0.f : g_c[cidx];
            const float cn = sigf(z[1]) * cold + sigf(z[0]) * tanhf(z[2]);
            const float hn = sigf(z[3]) * tanhf(cn);
            g_c[cidx] = cn;
            st_wt(&g_hT[((size_t)t * HSZ + jglob) * BATCH + bglob], hn);
            wait_vm0();
            __syncthreads();
            if (tid == 0) st_flag(&g_fA[(size_t)t * NWG_A + w], t + 1);
            if (t + 1 < TSTEPS) stageX(t + 1);
        }
    } else if (w < NWG_A + NWG_B) {
        // ================= phase B: read head + output + w_u/w_w =================
        const int bwg = w - NWG_A;
        const int grp = tid >> 7, lm = tid & 127;
        const int bB = bwg * 2 + grp;
        float* s_M = (float*)s_x4;    // 128 KB: M(t) staged in LDS
        float* s_h2 = s_aux;          // [2][256]
        float* s_wr2 = s_aux + 512;   // [2][128]
        float wwreg = (lm == 0) ? OMG_C : 0.f;
        float wureg = 0.f;

        for (int t = 0; t < TSTEPS; ++t) {
            // ---- early M(t) prefetch: ready at C(t-1) flag, before h(t) exists ----
            if (t > 0) {
                if (wv == 1) wait_flags(g_fC + (size_t)(t - 1) * NWG_C, NWG_C, t, lane);
                __syncthreads();
                asm volatile("" ::: "memory");
                float4 mt[32];
                const float4* msrc = (const float4*)&g_M[(size_t)t * MEMN * HSZ];
#pragma unroll
                for (int i = 0; i < 32; ++i) mt[i] = msrc[i * 256 + tid];
                float4* md = (float4*)s_M;
#pragma unroll
                for (int i = 0; i < 32; ++i) md[i * 256 + tid] = mt[i];
            }
            if (wv == 0) wait_flags(g_fA + (size_t)t * NWG_A, NWG_A, t + 1, lane);
            __syncthreads();
            asm volatile("" ::: "memory");
            s_h2[grp * 256 + lm] = g_hT[((size_t)t * HSZ + lm) * BATCH + bB];
            s_h2[grp * 256 + lm + 128] = g_hT[((size_t)t * HSZ + lm + 128) * BATCH + bB];
            __syncthreads();
            const float hv0 = s_h2[grp * 256 + lm], hv1 = s_h2[grp * 256 + lm + 128];
            const float hnorm = sqrtf(grpsum(hv0 * hv0 + hv1 * hv1));
            float sc = 0.f;
            if (t > 0) {
                const float4* mrow = (const float4*)&s_M[(size_t)lm * HSZ];
                const float4* h4 = (const float4*)&s_h2[grp * 256];
                const int sw = lm & 7;
                float a = 0.f;
#pragma unroll 8
                for (int c = 0; c < 64; ++c) {
                    const int ci = c ^ sw;  // bank-spread; same term set, block-permuted order
                    const float4 m4 = mrow[ci], x4 = h4[ci];
                    a += m4.x * x4.x + m4.y * x4.y + m4.z * x4.z + m4.w * x4.w;
                }
                const float mn = g_Mn[(size_t)t * MEMN + lm];
                sc = a / (hnorm * mn + 1e-8f);
            }
            const float mx = grpmax(sc);
            const float ev = expf(sc - mx);
            const float es = grpsum(ev);
            const float wr = ev / es;
            s_wr2[grp * 128 + lm] = wr;
            __syncthreads();
            float rd0 = 0.f, rd1 = 0.f;
            if (t > 0) {
#pragma unroll 8
                for (int m = 0; m < 128; ++m) {
                    const float mv = s_M[m * HSZ + tid];
                    rd0 += s_wr2[m] * mv;
                    rd1 += s_wr2[128 + m] * mv;
                }
            }
            const int b0 = bwg * 2, b1 = b0 + 1;
            float* o0 = out + ((size_t)b0 * TSTEPS + t) * 512;
            float* o1 = out + ((size_t)b1 * TSTEPS + t) * 512;
            o0[tid] = s_h2[tid];
            o1[tid] = s_h2[256 + tid];
            o0[256 + tid] = rd0;
            o1[256 + tid] = rd1;
            // w_u(t+1) = l2norm(gamma*w_u + w_r + w_w(t)); w_w(t+1) from argmin
            const float un = GAMMA_C * wureg + wr + wwreg;
            const float un2 = grpsum(un * un);
            const float us = 1.0f / fmaxf(sqrtf(un2), 1e-12f);
            const float wun = un * us;
            wureg = wun;
            unsigned long long key =
                (((unsigned long long)__float_as_uint(wun)) << 32) | (unsigned)lm;
            const unsigned long long mk = grpminu(key);
            const int amin = (int)(mk & 0xffffffffu);
            const float wwn = GATE_C * wr + ((lm == amin) ? OMG_C : 0.f);
            wwreg = wwn;
            if (t + 1 < TSTEPS)
                st_wt(&g_ww[((size_t)(t + 1) * BATCH + bB) * MEMN + lm], wwn);
            wait_vm0();
            __syncthreads();
            if (tid == 0) st_flag(&g_fB[(size_t)t * NWG_B + bwg], t + 1);
        }
    } else {
        // ================= phase C: M(t+1) = l2norm(M(t) + ww(t)^T h(t)) =================
        const int cwg = w - NWG_A - NWG_B;
        const int m0 = cwg * 4;
        float* s_wwc = s_aux;  // [4][128]
        float mreg[4] = {0.f, 0.f, 0.f, 0.f};  // own M rows stay in registers

        for (int t = 0; t < TSTEPS - 1; ++t) {
            // ---- early ww(t) stage: ready at B(t-1) flag ----
            if (wv == 1 && t > 0) wait_flags(g_fB + (size_t)(t - 1) * NWG_B, NWG_B, t, lane);
            __syncthreads();
            asm volatile("" ::: "memory");
            {
                const int e0 = tid, e1 = tid + 256;
                float v0, v1;
                if (t > 0) {
                    v0 = g_ww[((size_t)t * BATCH + (e0 >> 2)) * MEMN + m0 + (e0 & 3)];
                    v1 = g_ww[((size_t)t * BATCH + (e1 >> 2)) * MEMN + m0 + (e1 & 3)];
                } else {
                    v0 = (m0 + (e0 & 3) == 0) ? OMG_C : 0.f;
                    v1 = (m0 + (e1 & 3) == 0) ? OMG_C : 0.f;
                }
                s_wwc[(e0 & 3) * 128 + (e0 >> 2)] = v0;
                s_wwc[(e1 & 3) * 128 + (e1 >> 2)] = v1;
            }
            if (wv == 0) wait_flags(g_fA + (size_t)t * NWG_A, NWG_A, t + 1, lane);
            __syncthreads();
            asm volatile("" ::: "memory");
            // hT row read, full MLP
            float4 hb[32];
            const float4* ht4 = (const float4*)&g_hT[((size_t)t * HSZ + tid) * BATCH];
#pragma unroll
            for (int q = 0; q < 32; ++q) hb[q] = ht4[q];
            float macc[4];
#pragma unroll
            for (int mi = 0; mi < 4; ++mi) macc[mi] = mreg[mi];
#pragma unroll
            for (int b4 = 0; b4 < 32; ++b4) {
                const float4 hv4 = hb[b4];
#pragma unroll
                for (int mi = 0; mi < 4; ++mi) {
                    const float* wc = &s_wwc[mi * 128 + b4 * 4];
                    macc[mi] += wc[0] * hv4.x + wc[1] * hv4.y + wc[2] * hv4.z + wc[3] * hv4.w;
                }
            }
            float nr[4];
            red256sum4(macc[0] * macc[0], macc[1] * macc[1],
                       macc[2] * macc[2], macc[3] * macc[3], nr);
#pragma unroll
            for (int mi = 0; mi < 4; ++mi) {
                const float nrm = sqrtf(nr[mi]);
                const float scale = 1.0f / fmaxf(nrm, 1e-12f);
                const float vo = macc[mi] * scale;
                mreg[mi] = vo;
                st_wt(&g_M[((size_t)(t + 1) * MEMN + m0 + mi) * HSZ + tid], vo);
                if (tid == 0) st_wt(&g_Mn[(size_t)(t + 1) * MEMN + m0 + mi], nrm * scale);
            }
            wait_vm0();
            __syncthreads();
            if (tid == 0) st_flag(&g_fC[(size_t)t * NWG_C + cwg], t + 1);
        }
    }
}

extern "C" void kernel_launch(void* const* d_in, const int* in_sizes, int n_in,
                              void* d_out, int out_size, void* d_ws, size_t ws_size,
                              hipStream_t stream) {
    const float* X   = (const float*)d_in[0];
    const float* Wih = (const float*)d_in[1];
    const float* Whh = (const float*)d_in[2];
    const float* bih = (const float*)d_in[3];
    const float* bhh = (const float*)d_in[4];
    float* out = (float*)d_out;
    (void)in_sizes; (void)n_in; (void)out_size; (void)d_ws; (void)ws_size;

    hipLaunchKernelGGL(reset_ctrl_kernel, dim3(224), dim3(256), 0, stream);
    hipLaunchKernelGGL(mann_persist, dim3(NWG), dim3(NTHR), 0, stream,
                       X, Wih, Whh, bih, bhh, out);
}

// Round 7
// 23694.473 us; speedup vs baseline: 1.2791x; 1.0417x over previous
//
#include <hip/hip_runtime.h>
#include <math.h>

#define BATCH 128
#define TSTEPS 1024
#define INSZ 256
#define HSZ 256
#define MEMN 128

#define NWG_A 128
#define NWG_B 64
#define NWG_C 32
#define NWG 256
#define NTHR 256

#define GATE_C 0.40131233988754794f
#define OMG_C  (1.0f - GATE_C)
#define GAMMA_C 0.3f

// ---- per-step state, unique slot per t (write-through produced, cached-read consumed) ----
__device__ float g_hT[(size_t)TSTEPS * HSZ * BATCH];   // hT(t)[j][b]
__device__ float g_M [(size_t)TSTEPS * MEMN * HSZ];    // M(t)[m][j], slots 1..1023
__device__ float g_Mn[(size_t)TSTEPS * MEMN];          // Mn(t)[m],  slots 1..1023
__device__ float g_ww[(size_t)TSTEPS * BATCH * MEMN];  // ww(t)[b][m], slots 1..1023
// ---- per-WG completion flags: NO RMWs anywhere (plain bypass stores + scans) ----
__device__ int g_fA[TSTEPS * NWG_A];
__device__ int g_fB[TSTEPS * NWG_B];
__device__ int g_fC[TSTEPS * NWG_C];

__global__ void reset_ctrl_kernel() {
    const int gt = blockIdx.x * 256 + threadIdx.x, gn = gridDim.x * 256;
    for (int i = gt; i < TSTEPS * NWG_A; i += gn)
        __hip_atomic_store(&g_fA[i], 0, __ATOMIC_RELAXED, __HIP_MEMORY_SCOPE_AGENT);
    for (int i = gt; i < TSTEPS * NWG_B; i += gn)
        __hip_atomic_store(&g_fB[i], 0, __ATOMIC_RELAXED, __HIP_MEMORY_SCOPE_AGENT);
    for (int i = gt; i < TSTEPS * NWG_C; i += gn)
        __hip_atomic_store(&g_fC[i], 0, __ATOMIC_RELAXED, __HIP_MEMORY_SCOPE_AGENT);
}

__device__ __forceinline__ float sigf(float x) { return 1.0f / (1.0f + expf(-x)); }

__device__ __forceinline__ void st_wt(float* p, float v) {
    __hip_atomic_store(p, v, __ATOMIC_RELAXED, __HIP_MEMORY_SCOPE_AGENT);
}
__device__ __forceinline__ void st_flag(int* p, int v) {
    __hip_atomic_store(p, v, __ATOMIC_RELAXED, __HIP_MEMORY_SCOPE_AGENT);
}
__device__ __forceinline__ void wait_vm0() { asm volatile("s_waitcnt vmcnt(0)" ::: "memory"); }

// wave-cooperative flag scan: each lane checks n/64 slots
__device__ __forceinline__ void wait_flags(int* f, int n, int want, int lane) {
    int it = 0;
    for (;;) {
        bool ok = true;
        for (int i = lane; i < n; i += 64)
            ok &= (__hip_atomic_load(&f[i], __ATOMIC_RELAXED, __HIP_MEMORY_SCOPE_AGENT) == want);
        if (__all(ok)) break;
        __builtin_amdgcn_s_sleep(1);
        if (++it > (1 << 22)) break;  // hang valve
    }
}

__global__ void __launch_bounds__(NTHR, 1)
mann_persist(const float* __restrict__ X, const float* __restrict__ Wih,
             const float* __restrict__ Whh, const float* __restrict__ bih,
             const float* __restrict__ bhh, float* __restrict__ out) {
    __shared__ float4 s_x4[64 * 128];   // A: xh tiles (128 KB); B aliases as s_M
    __shared__ float s_aux[4096];       // A: partials; B/C carve
    __shared__ float s_red8[8];
    __shared__ float s_red16[16];
    __shared__ unsigned long long s_redu8[8];

    const int w = blockIdx.x, tid = threadIdx.x;
    const int lane = tid & 63, wv = tid >> 6;
    const int cls = w & 7, idx8 = w >> 3;   // XCD class (assuming bid%8 ~ XCD), index within class

    // ---- reductions ----
    auto grpsum = [&](float v) -> float {
#pragma unroll
        for (int o = 32; o; o >>= 1) v += __shfl_xor(v, o, 64);
        if (lane == 0) s_red8[wv] = v;
        __syncthreads();
        float r = s_red8[(tid >> 7) * 2] + s_red8[(tid >> 7) * 2 + 1];
        __syncthreads();
        return r;
    };
    auto grpmax = [&](float v) -> float {
#pragma unroll
        for (int o = 32; o; o >>= 1) v = fmaxf(v, __shfl_xor(v, o, 64));
        if (lane == 0) s_red8[wv] = v;
        __syncthreads();
        float r = fmaxf(s_red8[(tid >> 7) * 2], s_red8[(tid >> 7) * 2 + 1]);
        __syncthreads();
        return r;
    };
    auto grpminu = [&](unsigned long long v) -> unsigned long long {
#pragma unroll
        for (int o = 32; o; o >>= 1) {
            unsigned long long o2 = __shfl_xor(v, o, 64);
            v = (o2 < v) ? o2 : v;
        }
        if (lane == 0) s_redu8[wv] = v;
        __syncthreads();
        unsigned long long a = s_redu8[(tid >> 7) * 2], b2 = s_redu8[(tid >> 7) * 2 + 1];
        unsigned long long r = (a < b2) ? a : b2;
        __syncthreads();
        return r;
    };
    auto red256sum4 = [&](float v0, float v1, float v2, float v3, float (&r)[4]) {
#pragma unroll
        for (int o = 32; o; o >>= 1) {
            v0 += __shfl_xor(v0, o, 64);
            v1 += __shfl_xor(v1, o, 64);
            v2 += __shfl_xor(v2, o, 64);
            v3 += __shfl_xor(v3, o, 64);
        }
        if (lane == 0) {
            s_red16[wv * 4 + 0] = v0; s_red16[wv * 4 + 1] = v1;
            s_red16[wv * 4 + 2] = v2; s_red16[wv * 4 + 3] = v3;
        }
        __syncthreads();
#pragma unroll
        for (int k = 0; k < 4; ++k)
            r[k] = (s_red16[0 * 4 + k] + s_red16[1 * 4 + k]) +
                   (s_red16[2 * 4 + k] + s_red16[3 * 4 + k]);
        __syncthreads();
    };

    if (cls < 4) {
        // ================= phase A: LSTM cell =================
        // XCD-aligned: all WGs of one class share bb (same batch-half -> per-XCD dedup)
        const int aidx = cls * 32 + idx8;             // flag slot [0,128)
        const int bb = cls >> 1;                      // batch half
        const int jb = (cls & 1) * 32 + idx8;         // j-quad [0,64)
        const int bglob = bb * 64 + lane;
        float biasA[4];
#pragma unroll
        for (int g = 0; g < 4; ++g) {
            const int row = g * HSZ + jb * 4 + wv;
            biasA[g] = bih[row] + bhh[row];
        }

        auto loadXreg = [&](int t, float4 (&xr)[16]) {
            const int kq = tid & 63, bofs = tid >> 6;
#pragma unroll
            for (int rep = 0; rep < 16; ++rep) {
                const int b = rep * 4 + bofs;
                xr[rep] = *(const float4*)(X + ((size_t)(bb * 64 + b) * TSTEPS + t) * INSZ + kq * 4);
            }
        };
        auto storeXlds = [&](float4 (&xr)[16]) {
            const int kq = tid & 63, bofs = tid >> 6;
#pragma unroll
            for (int rep = 0; rep < 16; ++rep) {
                const int b = rep * 4 + bofs;
                s_x4[b * 128 + (kq ^ (b & 7))] = xr[rep];
            }
        };
        auto computeRegion = [&](float (&acc)[16], const float* __restrict__ Wb, const int kofs) {
            const int kbase = kofs + wv * 64;
#pragma unroll 4
            for (int k4 = 0; k4 < 16; ++k4) {
                const int kg = kbase + k4 * 4;
                const float4 xv = s_x4[lane * 128 + ((kg >> 2) ^ (lane & 7))];
                const int kl = kg - kofs;
#pragma unroll
                for (int rr = 0; rr < 16; ++rr) {
                    const int grow = (rr >> 2) * HSZ + jb * 4 + (rr & 3);
                    const float4 wv4 = *(const float4*)(Wb + (size_t)grow * 256 + kl);
                    acc[rr] += wv4.x * xv.x + wv4.y * xv.y + wv4.z * xv.z + wv4.w * xv.w;
                }
            }
        };

        {   // stage X(0)
            float4 xr[16];
            loadXreg(0, xr);
            storeXlds(xr);
        }
        __syncthreads();
        float creg = 0.f;

        for (int t = 0; t < TSTEPS; ++t) {
            float acc[16];
#pragma unroll
            for (int i = 0; i < 16; ++i) acc[i] = 0.f;
            const bool pf = (t + 1 < TSTEPS);
            float4 xr[16];
            if (pf) loadXreg(t + 1, xr);            // issue early, no wait
            computeRegion(acc, Wih, 0);             // consumes X(t); flag-independent
            if (t > 0) {
                wait_flags(g_fA + (size_t)(t - 1) * NWG_A + wv * 32, 32, t, lane);
                __syncthreads();                    // all waves: flags seen + X(t) dead
                asm volatile("" ::: "memory");
                float4 hv[16];
#pragma unroll
                for (int rep = 0; rep < 16; ++rep) {  // h(t-1) gather: 64 coalesced dwords
                    const int j0 = (wv * 16 + rep) * 4;
                    const size_t base = ((size_t)(t - 1) * HSZ + j0) * BATCH + bglob;
                    float4 v;
                    v.x = g_hT[base];
                    v.y = g_hT[base + BATCH];
                    v.z = g_hT[base + 2 * BATCH];
                    v.w = g_hT[base + 3 * BATCH];
                    hv[rep] = v;
                }
                if (pf) storeXlds(xr);              // X(t+1) into dead X-region
#pragma unroll
                for (int rep = 0; rep < 16; ++rep)
                    s_x4[lane * 128 + ((64 + wv * 16 + rep) ^ (lane & 7))] = hv[rep];
            } else {
                __syncthreads();                    // X(t) dead
                if (pf) storeXlds(xr);
                const float4 z4 = make_float4(0.f, 0.f, 0.f, 0.f);
#pragma unroll
                for (int rep = 0; rep < 16; ++rep)
                    s_x4[lane * 128 + ((64 + wv * 16 + rep) ^ (lane & 7))] = z4;
            }
            __syncthreads();
            computeRegion(acc, Whh, 256);
#pragma unroll
            for (int rr = 0; rr < 16; ++rr) s_aux[(wv * 16 + rr) * 64 + lane] = acc[rr];
            __syncthreads();
            float z[4];
#pragma unroll
            for (int g = 0; g < 4; ++g) {
                const int rr = g * 4 + wv;
                z[g] = ((s_aux[rr * 64 + lane] + s_aux[(16 + rr) * 64 + lane]) +
                        (s_aux[(32 + rr) * 64 + lane] + s_aux[(48 + rr) * 64 + lane])) + biasA[g];
            }
            const int jglob = jb * 4 + wv;
            const float cn = sigf(z[1]) * creg + sigf(z[0]) * tanhf(z[2]);
            const float hn = sigf(z[3]) * tanhf(cn);
            creg = cn;
            st_wt(&g_hT[((size_t)t * HSZ + jglob) * BATCH + bglob], hn);
            wait_vm0();
            __syncthreads();
            if (tid == 0) st_flag(&g_fA[(size_t)t * NWG_A + aidx], t + 1);
        }
    } else if (cls < 6) {
        // ================= phase B: read head + output + w_u/w_w =================
        const int bwg = (cls - 4) * 32 + idx8;   // [0,64)
        const int grp = tid >> 7, lm = tid & 127;
        const int bB = bwg * 2 + grp;
        float* s_M = (float*)s_x4;    // 128 KB: M(t) staged in LDS
        float* s_h2 = s_aux;          // [2][256]
        float* s_wr2 = s_aux + 512;   // [2][128]
        float wwreg = (lm == 0) ? OMG_C : 0.f;
        float wureg = 0.f;

        for (int t = 0; t < TSTEPS; ++t) {
            // ---- early M(t) prefetch: ready at C(t-1) flag, before h(t) exists ----
            if (t > 0) {
                if (wv == 1) wait_flags(g_fC + (size_t)(t - 1) * NWG_C, NWG_C, t, lane);
                __syncthreads();
                asm volatile("" ::: "memory");
                float4 mt[32];
                const float4* msrc = (const float4*)&g_M[(size_t)t * MEMN * HSZ];
#pragma unroll
                for (int i = 0; i < 32; ++i) mt[i] = msrc[i * 256 + tid];
                float4* md = (float4*)s_M;
#pragma unroll
                for (int i = 0; i < 32; ++i) md[i * 256 + tid] = mt[i];
            }
            if (wv == 0) wait_flags(g_fA + (size_t)t * NWG_A, NWG_A, t + 1, lane);
            __syncthreads();
            asm volatile("" ::: "memory");
            s_h2[grp * 256 + lm] = g_hT[((size_t)t * HSZ + lm) * BATCH + bB];
            s_h2[grp * 256 + lm + 128] = g_hT[((size_t)t * HSZ + lm + 128) * BATCH + bB];
            __syncthreads();
            const float hv0 = s_h2[grp * 256 + lm], hv1 = s_h2[grp * 256 + lm + 128];
            const float hnorm = sqrtf(grpsum(hv0 * hv0 + hv1 * hv1));
            float sc = 0.f;
            if (t > 0) {
                const float4* mrow = (const float4*)&s_M[(size_t)lm * HSZ];
                const float4* h4 = (const float4*)&s_h2[grp * 256];
                const int sw = lm & 7;
                float a = 0.f;
#pragma unroll 8
                for (int c = 0; c < 64; ++c) {
                    const int ci = c ^ sw;
                    const float4 m4 = mrow[ci], x4 = h4[ci];
                    a += m4.x * x4.x + m4.y * x4.y + m4.z * x4.z + m4.w * x4.w;
                }
                const float mn = g_Mn[(size_t)t * MEMN + lm];
                sc = a / (hnorm * mn + 1e-8f);
            }
            const float mx = grpmax(sc);
            const float ev = expf(sc - mx);
            const float es = grpsum(ev);
            const float wr = ev / es;
            s_wr2[grp * 128 + lm] = wr;
            __syncthreads();
            float rd0 = 0.f, rd1 = 0.f;
            if (t > 0) {
#pragma unroll 8
                for (int m = 0; m < 128; ++m) {
                    const float mv = s_M[m * HSZ + tid];
                    rd0 += s_wr2[m] * mv;
                    rd1 += s_wr2[128 + m] * mv;
                }
            }
            const int b0 = bwg * 2, b1 = b0 + 1;
            float* o0 = out + ((size_t)b0 * TSTEPS + t) * 512;
            float* o1 = out + ((size_t)b1 * TSTEPS + t) * 512;
            o0[tid] = s_h2[tid];
            o1[tid] = s_h2[256 + tid];
            o0[256 + tid] = rd0;
            o1[256 + tid] = rd1;
            // w_u(t+1) = l2norm(gamma*w_u + w_r + w_w(t)); w_w(t+1) from argmin
            const float un = GAMMA_C * wureg + wr + wwreg;
            const float un2 = grpsum(un * un);
            const float us = 1.0f / fmaxf(sqrtf(un2), 1e-12f);
            const float wun = un * us;
            wureg = wun;
            unsigned long long key =
                (((unsigned long long)__float_as_uint(wun)) << 32) | (unsigned)lm;
            const unsigned long long mk = grpminu(key);
            const int amin = (int)(mk & 0xffffffffu);
            const float wwn = GATE_C * wr + ((lm == amin) ? OMG_C : 0.f);
            wwreg = wwn;
            if (t + 1 < TSTEPS)
                st_wt(&g_ww[((size_t)(t + 1) * BATCH + bB) * MEMN + lm], wwn);
            wait_vm0();
            __syncthreads();
            if (tid == 0) st_flag(&g_fB[(size_t)t * NWG_B + bwg], t + 1);
        }
    } else if (cls == 6) {
        // ================= phase C: M(t+1) = l2norm(M(t) + ww(t)^T h(t)) =================
        const int cwg = idx8;            // [0,32)
        const int m0 = cwg * 4;
        float* s_wwc = s_aux;  // [4][128]
        float mreg[4] = {0.f, 0.f, 0.f, 0.f};  // own M rows stay in registers

        for (int t = 0; t < TSTEPS - 1; ++t) {
            // ---- early ww(t) stage: ready at B(t-1) flag ----
            if (wv == 1 && t > 0) wait_flags(g_fB + (size_t)(t - 1) * NWG_B, NWG_B, t, lane);
            __syncthreads();
            asm volatile("" ::: "memory");
            {
                const int e0 = tid, e1 = tid + 256;
                float v0, v1;
                if (t > 0) {
                    v0 = g_ww[((size_t)t * BATCH + (e0 >> 2)) * MEMN + m0 + (e0 & 3)];
                    v1 = g_ww[((size_t)t * BATCH + (e1 >> 2)) * MEMN + m0 + (e1 & 3)];
                } else {
                    v0 = (m0 + (e0 & 3) == 0) ? OMG_C : 0.f;
                    v1 = (m0 + (e1 & 3) == 0) ? OMG_C : 0.f;
                }
                s_wwc[(e0 & 3) * 128 + (e0 >> 2)] = v0;
                s_wwc[(e1 & 3) * 128 + (e1 >> 2)] = v1;
            }
            if (wv == 0) wait_flags(g_fA + (size_t)t * NWG_A, NWG_A, t + 1, lane);
            __syncthreads();
            asm volatile("" ::: "memory");
            float4 hb[32];
            const float4* ht4 = (const float4*)&g_hT[((size_t)t * HSZ + tid) * BATCH];
#pragma unroll
            for (int q = 0; q < 32; ++q) hb[q] = ht4[q];
            float macc[4];
#pragma unroll
            for (int mi = 0; mi < 4; ++mi) macc[mi] = mreg[mi];
#pragma unroll
            for (int b4 = 0; b4 < 32; ++b4) {
                const float4 hv4 = hb[b4];
#pragma unroll
                for (int mi = 0; mi < 4; ++mi) {
                    const float* wc = &s_wwc[mi * 128 + b4 * 4];
                    macc[mi] += wc[0] * hv4.x + wc[1] * hv4.y + wc[2] * hv4.z + wc[3] * hv4.w;
                }
            }
            float nr[4];
            red256sum4(macc[0] * macc[0], macc[1] * macc[1],
                       macc[2] * macc[2], macc[3] * macc[3], nr);
#pragma unroll
            for (int mi = 0; mi < 4; ++mi) {
                const float nrm = sqrtf(nr[mi]);
                const float scale = 1.0f / fmaxf(nrm, 1e-12f);
                const float vo = macc[mi] * scale;
                mreg[mi] = vo;
                st_wt(&g_M[((size_t)(t + 1) * MEMN + m0 + mi) * HSZ + tid], vo);
                if (tid == 0) st_wt(&g_Mn[(size_t)(t + 1) * MEMN + m0 + mi], nrm * scale);
            }
            wait_vm0();
            __syncthreads();
            if (tid == 0) st_flag(&g_fC[(size_t)t * NWG_C + cwg], t + 1);
        }
    }
    // cls == 7: idle, exit
}

extern "C" void kernel_launch(void* const* d_in, const int* in_sizes, int n_in,
                              void* d_out, int out_size, void* d_ws, size_t ws_size,
                              hipStream_t stream) {
    const float* X   = (const float*)d_in[0];
    const float* Wih = (const float*)d_in[1];
    const float* Whh = (const float*)d_in[2];
    const float* bih = (const float*)d_in[3];
    const float* bhh = (const float*)d_in[4];
    float* out = (float*)d_out;
    (void)in_sizes; (void)n_in; (void)out_size; (void)d_ws; (void)ws_size;

    hipLaunchKernelGGL(reset_ctrl_kernel, dim3(224), dim3(256), 0, stream);
    hipLaunchKernelGGL(mann_persist, dim3(NWG), dim3(NTHR), 0, stream,
                       X, Wih, Whh, bih, bhh, out);
}